// Round 14
// baseline (316.010 us; speedup 1.0000x reference)
//
#include <hip/hip_runtime.h>
#include <hip/hip_bf16.h>

// Problem constants: B=4, L=2048, d_model=d_value=512, H=8, E=64, d4=2048.
// External inputs/output fp32. Internal compute: bf16 MFMA.
//
// R13: conv_in deleted (qkv fp32-direct BK=32), XCD remap (verified, 309.0).
// R14: all N=512 GEMMs (Wo, FFN2, Wl) moved from the 64x128 tile to the
// 128x128 2-phase kernel: 65 F/B vs 44 F/B staged-compute density, 2x
// MFMA per barrier cadence; grid (4,64)=256 blocks = exactly 1/CU, 2-phase
// hides staging intra-block. gemm_mfma64 deleted.

typedef __attribute__((ext_vector_type(8))) short sh8;    // 8 bf16 (A/B frag)
typedef __attribute__((ext_vector_type(4))) float f32x4;  // C/D frag

#define QSCALE 0.18033688011110543f   // 0.125 * log2(e): folded into Q projection

__device__ __forceinline__ void storeOut(float* p, float v) { *p = v; }
__device__ __forceinline__ void storeOut(__hip_bfloat16* p, float v) { *p = __float2bfloat16(v); }

// async global->LDS, 16 B per lane, wave-uniform LDS base (m97 pattern)
__device__ __forceinline__ void gl_lds16(const void* g, void* l) {
    __builtin_amdgcn_global_load_lds((const __attribute__((address_space(1))) void*)g,
                                     (__attribute__((address_space(3))) void*)l, 16, 0, 0);
}

// pack two fp32 into one dword of two bf16 (RNE)
__device__ __forceinline__ unsigned pk_bf16(float a, float b) {
    __hip_bfloat162 h = __float22bfloat162_rn(make_float2(a, b));
    return *(unsigned*)&h;
}
__device__ __forceinline__ float bf2f(unsigned short u) {
    unsigned x = (unsigned)u << 16;
    return *(float*)&x;
}
// 8 fp32 -> sh8 bf16 fragment
__device__ __forceinline__ sh8 pk8(float4 a, float4 b) {
    int4 iv = make_int4(pk_bf16(a.x, a.y), pk_bf16(a.z, a.w),
                        pk_bf16(b.x, b.y), pk_bf16(b.z, b.w));
    return *(sh8*)&iv;
}

// ---------------------------------------------------------------------------
// Weights fp32 -> bf16 into one contiguous ws region.
// Order: Wq,Wk,Wv,Wo,Wl,Wc1,Wc2 (3407872 elements).
// ---------------------------------------------------------------------------
struct WArg { const float* w[7]; unsigned short* wd; };
__global__ __launch_bounds__(256) void conv_w(WArg p)
{
    const int i = (blockIdx.x * 256 + threadIdx.x) * 4;
    if (i >= 3407872) return;
    const float* s; int off;
    if      (i < 262144)  { s = p.w[0]; off = i; }
    else if (i < 524288)  { s = p.w[1]; off = i - 262144; }
    else if (i < 786432)  { s = p.w[2]; off = i - 524288; }
    else if (i < 1048576) { s = p.w[3]; off = i - 786432; }
    else if (i < 1310720) { s = p.w[4]; off = i - 1048576; }
    else if (i < 2359296) { s = p.w[5]; off = i - 1310720; }
    else                  { s = p.w[6]; off = i - 2359296; }
    const float4 v = *(const float4*)(s + off);
    *(uint2*)(p.wd + i) = make_uint2(pk_bf16(v.x, v.y), pk_bf16(v.z, v.w));
}

// ---------------------------------------------------------------------------
// Batched QKV GEMM (grid.z = 0,1,2), fp32 A direct, BK=32, 2-PHASE.
// A fp32 staged coalesced: 8 rows/instr, 8 lanes/row (128 B), chunk-XOR
// over 8. W bf16: 16 rows/instr, 4 lanes/row (64 B), chunk-XOR over 4.
// z=0: scaled by QSCALE -> Qb. z=1 -> Kb. z=2 -> Vt[B*H,64,L] transposed.
// LDS 48 KB -> 2 blocks/CU.
// ---------------------------------------------------------------------------
struct QkvArg {
    const float *A0, *A1, *A2;
    const float *b0, *b1, *b2;
    unsigned short *C0, *C1;               // Qb, Kb [B,L,H,64]
    unsigned short *Vt;                    // [B*H,64,L]
};
__global__ __launch_bounds__(256, 2) void gemm_qkv(QkvArg ar, const unsigned short* __restrict__ Wall,
                                                   int M, int N, int K)
{
    const int z = blockIdx.z;
    const float* A = z == 0 ? ar.A0 : (z == 1 ? ar.A1 : ar.A2);
    const unsigned short* W = Wall + (size_t)z * 262144;
    const float* bias = z == 0 ? ar.b0 : (z == 1 ? ar.b1 : ar.b2);

    __shared__ float AsF[2][4096];            // [buf][row:128][chunk:8][4 fp32] 16 KB ea
    __shared__ unsigned short BsL[2][4096];   // [buf][row:128][chunk:4][8 bf16] 8 KB ea
    const int t    = threadIdx.x;
    const int wave = t >> 6, lane = t & 63;
    const int quad = lane >> 4, col = lane & 15;
    const int wm   = wave >> 1, wn = wave & 1;
    const int m0   = blockIdx.y * 128, n0 = blockIdx.x * 128;

    auto stage = [&](int k0, int buf) {
        #pragma unroll
        for (int seg = 0; seg < 4; seg++) {        // A: 8 rows/instr
            const int r0  = (seg * 4 + wave) * 8;  // wave-uniform
            const int row = r0 + (lane >> 3);
            const int ck  = (lane & 7) ^ (row & 7);
            gl_lds16(A + (size_t)(m0 + row) * K + k0 + ck * 4, &AsF[buf][r0 * 32]);
        }
        #pragma unroll
        for (int seg = 0; seg < 2; seg++) {        // W: 16 rows/instr
            const int r0  = (seg * 4 + wave) * 16;
            const int row = r0 + (lane >> 2);
            const int ck  = (lane & 3) ^ (row & 3);
            gl_lds16(W + (size_t)(n0 + row) * K + k0 + ck * 8, &BsL[buf][r0 * 32]);
        }
    };

    f32x4 acc[4][4];
    #pragma unroll
    for (int mt = 0; mt < 4; mt++)
        #pragma unroll
        for (int nt = 0; nt < 4; nt++)
            acc[mt][nt] = (f32x4){0.f, 0.f, 0.f, 0.f};

    stage(0, 0);
    __syncthreads();
    int cur = 0;
    for (int k0 = 0; k0 < K; k0 += 32) {
        if (k0 + 32 < K) stage(k0 + 32, cur ^ 1);
        sh8 af[4], bf[4];
        #pragma unroll
        for (int mt = 0; mt < 4; mt++) {
            const int mr = wm * 64 + mt * 16 + col;
            const int q0 = quad * 2;
            const int m8 = mr & 7;
            float4 f0 = *(const float4*)&AsF[cur][mr * 32 + ((q0 ^ m8) << 2)];
            float4 f1 = *(const float4*)&AsF[cur][mr * 32 + (((q0 + 1) ^ m8) << 2)];
            af[mt] = pk8(f0, f1);
        }
        #pragma unroll
        for (int nt = 0; nt < 4; nt++) {
            const int nr = wn * 64 + nt * 16 + col;
            bf[nt] = *(const sh8*)&BsL[cur][nr * 32 + ((quad ^ (nr & 3)) << 3)];
        }
        #pragma unroll
        for (int mt = 0; mt < 4; mt++)
            #pragma unroll
            for (int nt = 0; nt < 4; nt++)
                acc[mt][nt] = __builtin_amdgcn_mfma_f32_16x16x32_bf16(af[mt], bf[nt], acc[mt][nt], 0, 0, 0);
        __syncthreads();
        cur ^= 1;
    }

    if (z < 2) {
        unsigned short* C = z == 0 ? ar.C0 : ar.C1;
        const float scale = z == 0 ? QSCALE : 1.0f;
        #pragma unroll
        for (int nt = 0; nt < 4; nt++) {
            const int cn = n0 + wn * 64 + nt * 16 + col;
            const float bj = bias[cn];
            #pragma unroll
            for (int mt = 0; mt < 4; mt++) {
                const int rm = m0 + wm * 64 + mt * 16 + quad * 4;
                #pragma unroll
                for (int reg = 0; reg < 4; reg++)
                    C[(size_t)(rm + reg) * N + cn] =
                        (unsigned short)__bfloat16_as_ushort(__float2bfloat16((acc[mt][nt][reg] + bj) * scale));
            }
        }
    } else {
        // V: write transposed [B*H, 64, L]; 4 consecutive s rows pack to 8 B.
        const int b = m0 >> 11;                    // L = 2048
        #pragma unroll
        for (int nt = 0; nt < 4; nt++) {
            const int cn = n0 + wn * 64 + nt * 16 + col;
            const int h = cn >> 6, e = cn & 63;
            const float bj = bias[cn];
            #pragma unroll
            for (int mt = 0; mt < 4; mt++) {
                const int s0r = (m0 + wm * 64 + mt * 16 + quad * 4) & 2047;
                float cv[4];
                #pragma unroll
                for (int reg = 0; reg < 4; reg++) cv[reg] = acc[mt][nt][reg] + bj;
                *(uint2*)(ar.Vt + ((size_t)(b * 8 + h) * 64 + e) * 2048 + s0r) =
                    make_uint2(pk_bf16(cv[0], cv[1]), pk_bf16(cv[2], cv[3]));
            }
        }
    }
}

// ---------------------------------------------------------------------------
// MFMA GEMM 128x128, BK=64, 2-PHASE + XCD-affinity remap (R13/R14).
// Used for FFN1 AND all N=512 GEMMs (Wo, FFN2, Wl).
// lin&7 selects XCD slot; all NB n-blocks of an A-panel land on one XCD.
// ---------------------------------------------------------------------------
template <typename TOUT, bool RELU>
__global__ __launch_bounds__(256, 2) void gemm_mfma(const unsigned short* __restrict__ A,
                                                    const unsigned short* __restrict__ W,
                                                    const float* __restrict__ bias,
                                                    TOUT* __restrict__ C,
                                                    int M, int N, int K)
{
    __shared__ unsigned short AsL[2][8192];   // [buf][row:128][chunk:8][8 bf16] swz
    __shared__ unsigned short BsL[2][8192];
    const int t    = threadIdx.x;
    const int wave = t >> 6, lane = t & 63;
    const int quad = lane >> 4, col = lane & 15;
    const int wm   = wave >> 1, wn = wave & 1;
    // XCD-affinity remap (MB divisible by 8)
    const int NB  = gridDim.x, MB = gridDim.y;
    const int lin = blockIdx.x + NB * blockIdx.y;
    const int mi  = (lin & 7) * (MB >> 3) + (lin >> 3) / NB;
    const int ni  = (lin >> 3) % NB;
    const int m0  = mi * 128, n0 = ni * 128;

    auto stage = [&](int k0, int buf) {
        #pragma unroll
        for (int seg = 0; seg < 4; seg++) {
            const int r0  = (seg * 4 + wave) * 8;  // wave-uniform
            const int row = r0 + (lane >> 3);
            const int ck  = (lane & 7) ^ (row & 7);
            gl_lds16(A + (size_t)(m0 + row) * K + k0 + ck * 8, &AsL[buf][r0 * 64]);
            gl_lds16(W + (size_t)(n0 + row) * K + k0 + ck * 8, &BsL[buf][r0 * 64]);
        }
    };

    f32x4 acc[4][4];
    #pragma unroll
    for (int mt = 0; mt < 4; mt++)
        #pragma unroll
        for (int nt = 0; nt < 4; nt++)
            acc[mt][nt] = (f32x4){0.f, 0.f, 0.f, 0.f};

    stage(0, 0);
    __syncthreads();
    int cur = 0;
    for (int k0 = 0; k0 < K; k0 += 64) {
        if (k0 + 64 < K) stage(k0 + 64, cur ^ 1);
        #pragma unroll
        for (int kc = 0; kc < 2; kc++) {
            sh8 af[4], bf[4];
            #pragma unroll
            for (int mt = 0; mt < 4; mt++) {
                const int ar = wm * 64 + mt * 16 + col;
                af[mt] = *(const sh8*)&AsL[cur][ar * 64 + (((kc * 4 + quad) ^ (ar & 7)) << 3)];
            }
            #pragma unroll
            for (int nt = 0; nt < 4; nt++) {
                const int nr = wn * 64 + nt * 16 + col;
                bf[nt] = *(const sh8*)&BsL[cur][nr * 64 + (((kc * 4 + quad) ^ (nr & 7)) << 3)];
            }
            #pragma unroll
            for (int mt = 0; mt < 4; mt++)
                #pragma unroll
                for (int nt = 0; nt < 4; nt++)
                    acc[mt][nt] = __builtin_amdgcn_mfma_f32_16x16x32_bf16(af[mt], bf[nt], acc[mt][nt], 0, 0, 0);
        }
        __syncthreads();
        cur ^= 1;
    }
    #pragma unroll
    for (int nt = 0; nt < 4; nt++) {
        const int cn = n0 + wn * 64 + nt * 16 + col;
        const float bj = bias[cn];
        #pragma unroll
        for (int mt = 0; mt < 4; mt++) {
            const int rm = m0 + wm * 64 + mt * 16 + quad * 4;
            #pragma unroll
            for (int reg = 0; reg < 4; reg++) {
                float cv = acc[mt][nt][reg] + bj;
                if (RELU) cv = fmaxf(cv, 0.f);
                storeOut(&C[(size_t)(rm + reg) * N + cn], cv);
            }
        }
    }
}

// ---------------------------------------------------------------------------
// MFMA flash attention v9 (causal, reverse-paired tiles, COALESCED staging).
// R6-verified config (~56 us; R10: structure is round-throughput-bound).
// ---------------------------------------------------------------------------
__global__ __launch_bounds__(256, 2) void attn_mfma(const unsigned short* __restrict__ Qb,
                                                    const unsigned short* __restrict__ Kb,
                                                    const unsigned short* __restrict__ Vt,
                                                    __hip_bfloat16* __restrict__ O,
                                                    int L)
{
    __shared__ unsigned short Ks[2][4096];       // [buf][key:64][e-chunk swz] 16 KB
    __shared__ unsigned short Vs[2][4096];       // [buf][e:64][key-chunk swz] 16 KB
    __shared__ unsigned short PsA[4][16][72];    // per wave [qrow:16][key:64+pad] 9 KB
    __shared__ unsigned short PsB[4][16][72];

    const int i    = blockIdx.x;                 // 0..15
    const int bh   = blockIdx.y;
    const int b    = bh >> 3, h = bh & 7;        // H = 8
    const int t    = threadIdx.x;
    const int w    = t >> 6, lane = t & 63;
    const int quad = lane >> 4, col = lane & 15;

    const int qtA = i, qtB = 31 - i;             // light / heavy tile
    const int qrowA = qtA * 64 + w * 16 + col;
    const int qrowB = qtB * 64 + w * 16 + col;
    const int S = 32 - i;                        // rounds (tile B needs all)

    const int srow = lane >> 3;                  // row offset within instr (0..7)
    const int scp  = lane & 7;                   // destination chunk

    sh8 qfA[2], qfB[2];
    {
        const size_t qa = ((size_t)(b * L + qrowA) * 8 + h) * 64;
        qfA[0] = *(const sh8*)(Qb + qa + quad * 8);
        qfA[1] = *(const sh8*)(Qb + qa + 32 + quad * 8);
        const size_t qb2 = ((size_t)(b * L + qrowB) * 8 + h) * 64;
        qfB[0] = *(const sh8*)(Qb + qb2 + quad * 8);
        qfB[1] = *(const sh8*)(Qb + qb2 + 32 + quad * 8);
    }

    f32x4 OA[4], OB[4];
    #pragma unroll
    for (int nt = 0; nt < 4; nt++) { OA[nt] = (f32x4){0.f,0.f,0.f,0.f}; OB[nt] = (f32x4){0.f,0.f,0.f,0.f}; }
    float lA = 0.f, lB = 0.f;

    {
        #pragma unroll
        for (int seg = 0; seg < 2; seg++) {
            const int r0  = (seg * 4 + w) * 8;   // wave-uniform row base
            const int row = r0 + srow;
            const int ck  = scp ^ (row & 7);     // source chunk (involution)
            gl_lds16(Kb + ((size_t)(b * L + row) * 8 + h) * 64 + ck * 8, &Ks[0][r0 * 64]);
            gl_lds16(Vt + (size_t)(bh * 64 + row) * L + ck * 8, &Vs[0][r0 * 64]);
        }
        __syncthreads();
    }

    int cur = 0;
    for (int r = 0; r < S; r++) {
        if (r + 1 < S) {
            const int k1 = (r + 1) * 64;
            #pragma unroll
            for (int seg = 0; seg < 2; seg++) {
                const int r0  = (seg * 4 + w) * 8;
                const int row = r0 + srow;
                const int ck  = scp ^ (row & 7);
                gl_lds16(Kb + ((size_t)(b * L + k1 + row) * 8 + h) * 64 + ck * 8, &Ks[cur ^ 1][r0 * 64]);
                gl_lds16(Vt + (size_t)(bh * 64 + row) * L + k1 + ck * 8, &Vs[cur ^ 1][r0 * 64]);
            }
        }

        const int k0 = r * 64;
        const bool actA  = (r <= i);
        const bool maskA = (r == i);
        const bool maskB = (r == S - 1);

        f32x4 stA[4], stB[4];
        const f32x4 zz = {0.f, 0.f, 0.f, 0.f};
        #pragma unroll
        for (int ntk = 0; ntk < 4; ntk++) {
            const int key = ntk * 16 + col;
            const int sw  = key & 7;
            sh8 kf0 = *(const sh8*)&Ks[cur][key * 64 + ((quad ^ sw) << 3)];
            sh8 kf1 = *(const sh8*)&Ks[cur][key * 64 + (((quad + 4) ^ sw) << 3)];
            f32x4 aB = __builtin_amdgcn_mfma_f32_16x16x32_bf16(kf0, qfB[0], zz, 0, 0, 0);
            stB[ntk] = __builtin_amdgcn_mfma_f32_16x16x32_bf16(kf1, qfB[1], aB, 0, 0, 0);
            if (actA) {
                f32x4 aA = __builtin_amdgcn_mfma_f32_16x16x32_bf16(kf0, qfA[0], zz, 0, 0, 0);
                stA[ntk] = __builtin_amdgcn_mfma_f32_16x16x32_bf16(kf1, qfA[1], aA, 0, 0, 0);
            }
        }

        {
            if (maskB) {
                #pragma unroll
                for (int ntk = 0; ntk < 4; ntk++)
                    #pragma unroll
                    for (int reg = 0; reg < 4; reg++)
                        if (k0 + ntk * 16 + quad * 4 + reg > qrowB) stB[ntk][reg] = -1e30f;
            }
            #pragma unroll
            for (int ntk = 0; ntk < 4; ntk++) {
                #pragma unroll
                for (int reg = 0; reg < 4; reg++)
                    stB[ntk][reg] = exp2f(stB[ntk][reg]);
                lB += (stB[ntk][0] + stB[ntk][1]) + (stB[ntk][2] + stB[ntk][3]);
                *(uint2*)&PsB[w][col][ntk * 16 + quad * 4] =
                    make_uint2(pk_bf16(stB[ntk][0], stB[ntk][1]), pk_bf16(stB[ntk][2], stB[ntk][3]));
            }
        }
        if (actA) {
            if (maskA) {
                #pragma unroll
                for (int ntk = 0; ntk < 4; ntk++)
                    #pragma unroll
                    for (int reg = 0; reg < 4; reg++)
                        if (k0 + ntk * 16 + quad * 4 + reg > qrowA) stA[ntk][reg] = -1e30f;
            }
            #pragma unroll
            for (int ntk = 0; ntk < 4; ntk++) {
                #pragma unroll
                for (int reg = 0; reg < 4; reg++)
                    stA[ntk][reg] = exp2f(stA[ntk][reg]);
                lA += (stA[ntk][0] + stA[ntk][1]) + (stA[ntk][2] + stA[ntk][3]);
                *(uint2*)&PsA[w][col][ntk * 16 + quad * 4] =
                    make_uint2(pk_bf16(stA[ntk][0], stA[ntk][1]), pk_bf16(stA[ntk][2], stA[ntk][3]));
            }
        }

        #pragma unroll
        for (int kchunk = 0; kchunk < 2; kchunk++) {
            sh8 pfB = *(const sh8*)&PsB[w][col][kchunk * 32 + quad * 8];
            sh8 pfA;
            if (actA) pfA = *(const sh8*)&PsA[w][col][kchunk * 32 + quad * 8];
            #pragma unroll
            for (int nt = 0; nt < 4; nt++) {
                const int e  = nt * 16 + col;
                sh8 vf = *(const sh8*)&Vs[cur][e * 64 + (((kchunk * 4 + quad) ^ (e & 7)) << 3)];
                OB[nt] = __builtin_amdgcn_mfma_f32_16x16x32_bf16(pfB, vf, OB[nt], 0, 0, 0);
                if (actA) OA[nt] = __builtin_amdgcn_mfma_f32_16x16x32_bf16(pfA, vf, OA[nt], 0, 0, 0);
            }
        }
        __syncthreads();
        cur ^= 1;
    }

    lA += __shfl_xor(lA, 16); lA += __shfl_xor(lA, 32);
    lB += __shfl_xor(lB, 16); lB += __shfl_xor(lB, 32);
    {
        const float li = 1.f / lA;
        float lr[4];
        #pragma unroll
        for (int reg = 0; reg < 4; reg++) lr[reg] = __shfl(li, quad * 4 + reg);
        #pragma unroll
        for (int reg = 0; reg < 4; reg++) {
            const int qr = qtA * 64 + w * 16 + quad * 4 + reg;
            #pragma unroll
            for (int nt = 0; nt < 4; nt++)
                O[((size_t)(b * L + qr) * 8 + h) * 64 + nt * 16 + col] =
                    __float2bfloat16(OA[nt][reg] * lr[reg]);
        }
    }
    {
        const float li = 1.f / lB;
        float lr[4];
        #pragma unroll
        for (int reg = 0; reg < 4; reg++) lr[reg] = __shfl(li, quad * 4 + reg);
        #pragma unroll
        for (int reg = 0; reg < 4; reg++) {
            const int qr = qtB * 64 + w * 16 + quad * 4 + reg;
            #pragma unroll
            for (int nt = 0; nt < 4; nt++)
                O[((size_t)(b * L + qr) * 8 + h) * 64 + nt * 16 + col] =
                    __float2bfloat16(OB[nt][reg] * lr[reg]);
        }
    }
}

// ---------------------------------------------------------------------------
// LayerNorm over last dim (512), bf16 in / bf16 out (R12 diet).
// x = f1 [+ f2] [+ rb(fp32)]. In-place safe (reads precede writes/thread).
// ---------------------------------------------------------------------------
__global__ __launch_bounds__(256) void layernorm_k(const unsigned short* __restrict__ f1,
                                                   const unsigned short* __restrict__ f2,
                                                   const float* __restrict__ rb,
                                                   const float* __restrict__ g,
                                                   const float* __restrict__ bb,
                                                   unsigned short* __restrict__ out16)
{
    const int row = blockIdx.x;
    const int t   = threadIdx.x;
    const size_t base = (size_t)row * 512;
    const int i0 = t * 2;

    const unsigned u1 = *(const unsigned*)(f1 + base + i0);
    float a0 = bf2f((unsigned short)(u1 & 0xffff));
    float a1 = bf2f((unsigned short)(u1 >> 16));
    if (f2) {
        const unsigned u2 = *(const unsigned*)(f2 + base + i0);
        a0 += bf2f((unsigned short)(u2 & 0xffff));
        a1 += bf2f((unsigned short)(u2 >> 16));
    }
    if (rb) { a0 += rb[base + i0]; a1 += rb[base + i0 + 1]; }

    float s = a0 + a1, ss = a0 * a0 + a1 * a1;
    #pragma unroll
    for (int off = 32; off > 0; off >>= 1) {
        s  += __shfl_xor(s, off);
        ss += __shfl_xor(ss, off);
    }
    __shared__ float red[16];
    const int lane = t & 63, wid = t >> 6;
    if (lane == 0) { red[wid] = s; red[8 + wid] = ss; }
    __syncthreads();
    if (t == 0) {
        const float S  = red[0] + red[1] + red[2] + red[3];
        const float SS = red[8] + red[9] + red[10] + red[11];
        const float mu = S * (1.f / 512.f);
        const float var = SS * (1.f / 512.f) - mu * mu;
        red[0] = mu;
        red[1] = rsqrtf(fmaxf(var, 0.f) + 1e-5f);
    }
    __syncthreads();
    const float mu = red[0], rstd = red[1];
    const float y0 = (a0 - mu) * rstd * g[i0]     + bb[i0];
    const float y1 = (a1 - mu) * rstd * g[i0 + 1] + bb[i0 + 1];
    *(unsigned*)(out16 + base + i0) = pk_bf16(y0, y1);
}

// ---------------------------------------------------------------------------
extern "C" void kernel_launch(void* const* d_in, const int* in_sizes, int n_in,
                              void* d_out, int out_size, void* d_ws, size_t ws_size,
                              hipStream_t stream)
{
    const float* q   = (const float*)d_in[0];
    const float* k   = (const float*)d_in[1];
    const float* v   = (const float*)d_in[2];
    const float* Wq  = (const float*)d_in[3];
    const float* bq  = (const float*)d_in[4];
    const float* Wk  = (const float*)d_in[5];
    const float* bk  = (const float*)d_in[6];
    const float* Wv  = (const float*)d_in[7];
    const float* bv  = (const float*)d_in[8];
    const float* Wo  = (const float*)d_in[9];
    const float* bo  = (const float*)d_in[10];
    const float* Wc1 = (const float*)d_in[11];
    const float* bc1 = (const float*)d_in[12];
    const float* Wc2 = (const float*)d_in[13];
    const float* bc2 = (const float*)d_in[14];
    const float* g1  = (const float*)d_in[15];
    const float* b1  = (const float*)d_in[16];
    const float* g2  = (const float*)d_in[17];
    const float* b2  = (const float*)d_in[18];
    const float* Wl  = (const float*)d_in[19];
    const float* bl  = (const float*)d_in[20];
    float* out = (float*)d_out;

    const int B = 4, L = 2048, H = 8;
    const int M = B * L;                        // 8192

    // Workspace map (bytes):
    //   A2b (8 MB) at 40370176 (Wo out, dead after LN1).
    //   Y2b (8 MB) at 48758784 (FFN2 out, dead after LN2).
    //   X1b (16 MB) at 73924608, live LN1 -> FFN1 -> LN2 (in-place).
    char* base = (char*)d_ws;
    unsigned short* Wall = (unsigned short*)(base + 0);          // 6.8 MB, live all
    unsigned short* Wob  = (unsigned short*)(base + 1572864);
    unsigned short* Wlb  = (unsigned short*)(base + 2097152);
    unsigned short* Wc1b = (unsigned short*)(base + 2621440);
    unsigned short* Wc2b = (unsigned short*)(base + 4718592);
    unsigned short* Qb   = (unsigned short*)(base + 6815744);    // -> dead after attn
    unsigned short* Kb   = (unsigned short*)(base + 15204352);   // -> dead after attn
    unsigned short* Vt   = (unsigned short*)(base + 23592960);   // -> dead after attn
    unsigned short* A1   = (unsigned short*)(base + 31981568);   // -> dead after Wo
    unsigned short* A2b  = (unsigned short*)(base + 40370176);   // att@Wo bf16 -> dead after LN1
    unsigned short* Y2b  = (unsigned short*)(base + 48758784);   // FFN2 out bf16 -> dead after LN2
    unsigned short* X1b  = (unsigned short*)(base + 73924608);   // x bf16, live to LN2 (in-place)
    unsigned short* X2b  = (unsigned short*)(base + 73924608);   // = X1b (in-place LN2)
    unsigned short* H1   = (unsigned short*)(base + 6815744);    // 33.5 MB over Qb..A1
    const dim3 blk(256);

    // 1: weights fp32 -> bf16
    WArg wa;
    wa.w[0] = Wq; wa.w[1] = Wk; wa.w[2] = Wv; wa.w[3] = Wo; wa.w[4] = Wl;
    wa.w[5] = Wc1; wa.w[6] = Wc2; wa.wd = Wall;
    conv_w<<<dim3(3328), blk, 0, stream>>>(wa);

    // 2: batched QKV projections (fp32 A direct, BK=32 2-phase)
    QkvArg qa;
    qa.A0 = q;  qa.A1 = k;  qa.A2 = v;
    qa.b0 = bq; qa.b1 = bk; qa.b2 = bv;
    qa.C0 = Qb; qa.C1 = Kb; qa.Vt = Vt;
    gemm_qkv<<<dim3(4, 64, 3), blk, 0, stream>>>(qa, Wall, M, 512, 512);

    // 3: flash attention v9 (R6-verified) -> bf16 A1
    attn_mfma<<<dim3(16, B * H), blk, 0, stream>>>(Qb, Kb, Vt, (__hip_bfloat16*)A1, L);

    // 4: att @ Wo^T + bo -> bf16 A2b (128^2 tile, R14)
    gemm_mfma<__hip_bfloat16, false><<<dim3(4, 64), blk, 0, stream>>>(A1, Wob, bo, (__hip_bfloat16*)A2b, M, 512, 512);

    // 5: x = LN(A2b + v) -> bf16 X1b
    layernorm_k<<<dim3(M), blk, 0, stream>>>(A2b, nullptr, v, g1, b1, X1b);

    // 6: h1 = relu(x @ Wc1^T + bc1) -> bf16 [M,2048]
    gemm_mfma<__hip_bfloat16, true><<<dim3(16, 64), blk, 0, stream>>>(X1b, Wc1b, bc1, (__hip_bfloat16*)H1, M, 2048, 512);

    // 7: y2 = h1 @ Wc2^T + bc2 -> bf16 Y2b (128^2 tile, R14)
    gemm_mfma<__hip_bfloat16, false><<<dim3(4, 64), blk, 0, stream>>>(H1, Wc2b, bc2, (__hip_bfloat16*)Y2b, M, 512, 2048);

    // 8: x2 = LN(X1b + Y2b) -> bf16, in place on X1b
    layernorm_k<<<dim3(M), blk, 0, stream>>>(X1b, Y2b, nullptr, g2, b2, X2b);

    // 9: out = x2 @ Wl^T + bl -> fp32 d_out (128^2 tile, R14)
    gemm_mfma<float, false><<<dim3(4, 64), blk, 0, stream>>>(X2b, Wlb, bl, out, M, 512, 512);
}

// Round 15
// 308.747 us; speedup vs baseline: 1.0235x; 1.0235x over previous
//
#include <hip/hip_runtime.h>
#include <hip/hip_bf16.h>

// Problem constants: B=4, L=2048, d_model=d_value=512, H=8, E=64, d4=2048.
// External inputs/output fp32. Internal compute: bf16 MFMA.
//
// R14 lesson: moving N=512 GEMMs to the 128^2 tile regressed (grid 256 =
// 1 block/CU -> no cross-block overlap at the per-K-step barrier; the
// 64x128 tile's 2 blocks/CU TLP beats the higher staged-compute density).
// R15 = exact revert to the R13 configuration (best verified, 309.0 us):
// qkv fp32-direct BK=32 2-phase; gemm_mfma (128^2) for FFN1 only;
// gemm_mfma64 (64x128) for Wo/FFN2/Wl; both with XCD-affinity remap;
// attn v9 (R6); bf16 intermediates + bf16 LN (R12).

typedef __attribute__((ext_vector_type(8))) short sh8;    // 8 bf16 (A/B frag)
typedef __attribute__((ext_vector_type(4))) float f32x4;  // C/D frag

#define QSCALE 0.18033688011110543f   // 0.125 * log2(e): folded into Q projection

__device__ __forceinline__ void storeOut(float* p, float v) { *p = v; }
__device__ __forceinline__ void storeOut(__hip_bfloat16* p, float v) { *p = __float2bfloat16(v); }

// async global->LDS, 16 B per lane, wave-uniform LDS base (m97 pattern)
__device__ __forceinline__ void gl_lds16(const void* g, void* l) {
    __builtin_amdgcn_global_load_lds((const __attribute__((address_space(1))) void*)g,
                                     (__attribute__((address_space(3))) void*)l, 16, 0, 0);
}

// pack two fp32 into one dword of two bf16 (RNE)
__device__ __forceinline__ unsigned pk_bf16(float a, float b) {
    __hip_bfloat162 h = __float22bfloat162_rn(make_float2(a, b));
    return *(unsigned*)&h;
}
__device__ __forceinline__ float bf2f(unsigned short u) {
    unsigned x = (unsigned)u << 16;
    return *(float*)&x;
}
// 8 fp32 -> sh8 bf16 fragment
__device__ __forceinline__ sh8 pk8(float4 a, float4 b) {
    int4 iv = make_int4(pk_bf16(a.x, a.y), pk_bf16(a.z, a.w),
                        pk_bf16(b.x, b.y), pk_bf16(b.z, b.w));
    return *(sh8*)&iv;
}

// ---------------------------------------------------------------------------
// Weights fp32 -> bf16 into one contiguous ws region.
// Order: Wq,Wk,Wv,Wo,Wl,Wc1,Wc2 (3407872 elements).
// ---------------------------------------------------------------------------
struct WArg { const float* w[7]; unsigned short* wd; };
__global__ __launch_bounds__(256) void conv_w(WArg p)
{
    const int i = (blockIdx.x * 256 + threadIdx.x) * 4;
    if (i >= 3407872) return;
    const float* s; int off;
    if      (i < 262144)  { s = p.w[0]; off = i; }
    else if (i < 524288)  { s = p.w[1]; off = i - 262144; }
    else if (i < 786432)  { s = p.w[2]; off = i - 524288; }
    else if (i < 1048576) { s = p.w[3]; off = i - 786432; }
    else if (i < 1310720) { s = p.w[4]; off = i - 1048576; }
    else if (i < 2359296) { s = p.w[5]; off = i - 1310720; }
    else                  { s = p.w[6]; off = i - 2359296; }
    const float4 v = *(const float4*)(s + off);
    *(uint2*)(p.wd + i) = make_uint2(pk_bf16(v.x, v.y), pk_bf16(v.z, v.w));
}

// ---------------------------------------------------------------------------
// Batched QKV GEMM (grid.z = 0,1,2), fp32 A direct, BK=32, 2-PHASE.
// A fp32 staged coalesced: 8 rows/instr, 8 lanes/row (128 B), chunk-XOR
// over 8. W bf16: 16 rows/instr, 4 lanes/row (64 B), chunk-XOR over 4.
// z=0: scaled by QSCALE -> Qb. z=1 -> Kb. z=2 -> Vt[B*H,64,L] transposed.
// LDS 48 KB -> 2 blocks/CU.
// ---------------------------------------------------------------------------
struct QkvArg {
    const float *A0, *A1, *A2;
    const float *b0, *b1, *b2;
    unsigned short *C0, *C1;               // Qb, Kb [B,L,H,64]
    unsigned short *Vt;                    // [B*H,64,L]
};
__global__ __launch_bounds__(256, 2) void gemm_qkv(QkvArg ar, const unsigned short* __restrict__ Wall,
                                                   int M, int N, int K)
{
    const int z = blockIdx.z;
    const float* A = z == 0 ? ar.A0 : (z == 1 ? ar.A1 : ar.A2);
    const unsigned short* W = Wall + (size_t)z * 262144;
    const float* bias = z == 0 ? ar.b0 : (z == 1 ? ar.b1 : ar.b2);

    __shared__ float AsF[2][4096];            // [buf][row:128][chunk:8][4 fp32] 16 KB ea
    __shared__ unsigned short BsL[2][4096];   // [buf][row:128][chunk:4][8 bf16] 8 KB ea
    const int t    = threadIdx.x;
    const int wave = t >> 6, lane = t & 63;
    const int quad = lane >> 4, col = lane & 15;
    const int wm   = wave >> 1, wn = wave & 1;
    const int m0   = blockIdx.y * 128, n0 = blockIdx.x * 128;

    auto stage = [&](int k0, int buf) {
        #pragma unroll
        for (int seg = 0; seg < 4; seg++) {        // A: 8 rows/instr
            const int r0  = (seg * 4 + wave) * 8;  // wave-uniform
            const int row = r0 + (lane >> 3);
            const int ck  = (lane & 7) ^ (row & 7);
            gl_lds16(A + (size_t)(m0 + row) * K + k0 + ck * 4, &AsF[buf][r0 * 32]);
        }
        #pragma unroll
        for (int seg = 0; seg < 2; seg++) {        // W: 16 rows/instr
            const int r0  = (seg * 4 + wave) * 16;
            const int row = r0 + (lane >> 2);
            const int ck  = (lane & 3) ^ (row & 3);
            gl_lds16(W + (size_t)(n0 + row) * K + k0 + ck * 8, &BsL[buf][r0 * 32]);
        }
    };

    f32x4 acc[4][4];
    #pragma unroll
    for (int mt = 0; mt < 4; mt++)
        #pragma unroll
        for (int nt = 0; nt < 4; nt++)
            acc[mt][nt] = (f32x4){0.f, 0.f, 0.f, 0.f};

    stage(0, 0);
    __syncthreads();
    int cur = 0;
    for (int k0 = 0; k0 < K; k0 += 32) {
        if (k0 + 32 < K) stage(k0 + 32, cur ^ 1);
        sh8 af[4], bf[4];
        #pragma unroll
        for (int mt = 0; mt < 4; mt++) {
            const int mr = wm * 64 + mt * 16 + col;
            const int q0 = quad * 2;
            const int m8 = mr & 7;
            float4 f0 = *(const float4*)&AsF[cur][mr * 32 + ((q0 ^ m8) << 2)];
            float4 f1 = *(const float4*)&AsF[cur][mr * 32 + (((q0 + 1) ^ m8) << 2)];
            af[mt] = pk8(f0, f1);
        }
        #pragma unroll
        for (int nt = 0; nt < 4; nt++) {
            const int nr = wn * 64 + nt * 16 + col;
            bf[nt] = *(const sh8*)&BsL[cur][nr * 32 + ((quad ^ (nr & 3)) << 3)];
        }
        #pragma unroll
        for (int mt = 0; mt < 4; mt++)
            #pragma unroll
            for (int nt = 0; nt < 4; nt++)
                acc[mt][nt] = __builtin_amdgcn_mfma_f32_16x16x32_bf16(af[mt], bf[nt], acc[mt][nt], 0, 0, 0);
        __syncthreads();
        cur ^= 1;
    }

    if (z < 2) {
        unsigned short* C = z == 0 ? ar.C0 : ar.C1;
        const float scale = z == 0 ? QSCALE : 1.0f;
        #pragma unroll
        for (int nt = 0; nt < 4; nt++) {
            const int cn = n0 + wn * 64 + nt * 16 + col;
            const float bj = bias[cn];
            #pragma unroll
            for (int mt = 0; mt < 4; mt++) {
                const int rm = m0 + wm * 64 + mt * 16 + quad * 4;
                #pragma unroll
                for (int reg = 0; reg < 4; reg++)
                    C[(size_t)(rm + reg) * N + cn] =
                        (unsigned short)__bfloat16_as_ushort(__float2bfloat16((acc[mt][nt][reg] + bj) * scale));
            }
        }
    } else {
        // V: write transposed [B*H, 64, L]; 4 consecutive s rows pack to 8 B.
        const int b = m0 >> 11;                    // L = 2048
        #pragma unroll
        for (int nt = 0; nt < 4; nt++) {
            const int cn = n0 + wn * 64 + nt * 16 + col;
            const int h = cn >> 6, e = cn & 63;
            const float bj = bias[cn];
            #pragma unroll
            for (int mt = 0; mt < 4; mt++) {
                const int s0r = (m0 + wm * 64 + mt * 16 + quad * 4) & 2047;
                float cv[4];
                #pragma unroll
                for (int reg = 0; reg < 4; reg++) cv[reg] = acc[mt][nt][reg] + bj;
                *(uint2*)(ar.Vt + ((size_t)(b * 8 + h) * 64 + e) * 2048 + s0r) =
                    make_uint2(pk_bf16(cv[0], cv[1]), pk_bf16(cv[2], cv[3]));
            }
        }
    }
}

// ---------------------------------------------------------------------------
// MFMA GEMM 128x128, BK=64 (FFN1), 2-PHASE + XCD-affinity remap (R13).
// lin&7 selects XCD slot; all NB n-blocks of an A-panel land on one XCD.
// ---------------------------------------------------------------------------
template <typename TOUT, bool RELU>
__global__ __launch_bounds__(256, 2) void gemm_mfma(const unsigned short* __restrict__ A,
                                                    const unsigned short* __restrict__ W,
                                                    const float* __restrict__ bias,
                                                    TOUT* __restrict__ C,
                                                    int M, int N, int K)
{
    __shared__ unsigned short AsL[2][8192];   // [buf][row:128][chunk:8][8 bf16] swz
    __shared__ unsigned short BsL[2][8192];
    const int t    = threadIdx.x;
    const int wave = t >> 6, lane = t & 63;
    const int quad = lane >> 4, col = lane & 15;
    const int wm   = wave >> 1, wn = wave & 1;
    // XCD-affinity remap (MB divisible by 8)
    const int NB  = gridDim.x, MB = gridDim.y;
    const int lin = blockIdx.x + NB * blockIdx.y;
    const int mi  = (lin & 7) * (MB >> 3) + (lin >> 3) / NB;
    const int ni  = (lin >> 3) % NB;
    const int m0  = mi * 128, n0 = ni * 128;

    auto stage = [&](int k0, int buf) {
        #pragma unroll
        for (int seg = 0; seg < 4; seg++) {
            const int r0  = (seg * 4 + wave) * 8;  // wave-uniform
            const int row = r0 + (lane >> 3);
            const int ck  = (lane & 7) ^ (row & 7);
            gl_lds16(A + (size_t)(m0 + row) * K + k0 + ck * 8, &AsL[buf][r0 * 64]);
            gl_lds16(W + (size_t)(n0 + row) * K + k0 + ck * 8, &BsL[buf][r0 * 64]);
        }
    };

    f32x4 acc[4][4];
    #pragma unroll
    for (int mt = 0; mt < 4; mt++)
        #pragma unroll
        for (int nt = 0; nt < 4; nt++)
            acc[mt][nt] = (f32x4){0.f, 0.f, 0.f, 0.f};

    stage(0, 0);
    __syncthreads();
    int cur = 0;
    for (int k0 = 0; k0 < K; k0 += 64) {
        if (k0 + 64 < K) stage(k0 + 64, cur ^ 1);
        #pragma unroll
        for (int kc = 0; kc < 2; kc++) {
            sh8 af[4], bf[4];
            #pragma unroll
            for (int mt = 0; mt < 4; mt++) {
                const int ar = wm * 64 + mt * 16 + col;
                af[mt] = *(const sh8*)&AsL[cur][ar * 64 + (((kc * 4 + quad) ^ (ar & 7)) << 3)];
            }
            #pragma unroll
            for (int nt = 0; nt < 4; nt++) {
                const int nr = wn * 64 + nt * 16 + col;
                bf[nt] = *(const sh8*)&BsL[cur][nr * 64 + (((kc * 4 + quad) ^ (nr & 7)) << 3)];
            }
            #pragma unroll
            for (int mt = 0; mt < 4; mt++)
                #pragma unroll
                for (int nt = 0; nt < 4; nt++)
                    acc[mt][nt] = __builtin_amdgcn_mfma_f32_16x16x32_bf16(af[mt], bf[nt], acc[mt][nt], 0, 0, 0);
        }
        __syncthreads();
        cur ^= 1;
    }
    #pragma unroll
    for (int nt = 0; nt < 4; nt++) {
        const int cn = n0 + wn * 64 + nt * 16 + col;
        const float bj = bias[cn];
        #pragma unroll
        for (int mt = 0; mt < 4; mt++) {
            const int rm = m0 + wm * 64 + mt * 16 + quad * 4;
            #pragma unroll
            for (int reg = 0; reg < 4; reg++) {
                float cv = acc[mt][nt][reg] + bj;
                if (RELU) cv = fmaxf(cv, 0.f);
                storeOut(&C[(size_t)(rm + reg) * N + cn], cv);
            }
        }
    }
}

// ---------------------------------------------------------------------------
// MFMA GEMM 64x128 tile, BK=64, 2-PHASE + XCD-affinity remap (R13).
// Used for Wo/FFN2/Wl (N=512: grid 512 = 2 blocks/CU, cross-block TLP).
// ---------------------------------------------------------------------------
template <typename TOUT, bool RELU>
__global__ __launch_bounds__(256, 2) void gemm_mfma64(const unsigned short* __restrict__ A,
                                                      const unsigned short* __restrict__ W,
                                                      const float* __restrict__ bias,
                                                      TOUT* __restrict__ C,
                                                      int M, int N, int K)
{
    __shared__ unsigned short AsL[2][4096];   // [buf][row:64][chunk:8][8 bf16] swz
    __shared__ unsigned short BsL[2][8192];
    const int t    = threadIdx.x;
    const int wave = t >> 6, lane = t & 63;
    const int quad = lane >> 4, col = lane & 15;
    const int wm   = wave >> 1, wn = wave & 1;
    // XCD-affinity remap (MB divisible by 8)
    const int NB  = gridDim.x, MB = gridDim.y;
    const int lin = blockIdx.x + NB * blockIdx.y;
    const int mi  = (lin & 7) * (MB >> 3) + (lin >> 3) / NB;
    const int ni  = (lin >> 3) % NB;
    const int m0  = mi * 64, n0 = ni * 128;

    auto stage = [&](int k0, int buf) {
        #pragma unroll
        for (int seg = 0; seg < 2; seg++) {
            const int r0  = (seg * 4 + wave) * 8;  // wave-uniform, 0..56
            const int row = r0 + (lane >> 3);
            const int ck  = (lane & 7) ^ (row & 7);
            gl_lds16(A + (size_t)(m0 + row) * K + k0 + ck * 8, &AsL[buf][r0 * 64]);
        }
        #pragma unroll
        for (int seg = 0; seg < 4; seg++) {
            const int r0  = (seg * 4 + wave) * 8;
            const int row = r0 + (lane >> 3);
            const int ck  = (lane & 7) ^ (row & 7);
            gl_lds16(W + (size_t)(n0 + row) * K + k0 + ck * 8, &BsL[buf][r0 * 64]);
        }
    };

    f32x4 acc[2][4];
    #pragma unroll
    for (int mt = 0; mt < 2; mt++)
        #pragma unroll
        for (int nt = 0; nt < 4; nt++)
            acc[mt][nt] = (f32x4){0.f, 0.f, 0.f, 0.f};

    stage(0, 0);
    __syncthreads();
    int cur = 0;
    for (int k0 = 0; k0 < K; k0 += 64) {
        if (k0 + 64 < K) stage(k0 + 64, cur ^ 1);
        #pragma unroll
        for (int kc = 0; kc < 2; kc++) {
            sh8 af[2], bf[4];
            #pragma unroll
            for (int mt = 0; mt < 2; mt++) {
                const int ar = wm * 32 + mt * 16 + col;
                af[mt] = *(const sh8*)&AsL[cur][ar * 64 + (((kc * 4 + quad) ^ (ar & 7)) << 3)];
            }
            #pragma unroll
            for (int nt = 0; nt < 4; nt++) {
                const int nr = wn * 64 + nt * 16 + col;
                bf[nt] = *(const sh8*)&BsL[cur][nr * 64 + (((kc * 4 + quad) ^ (nr & 7)) << 3)];
            }
            #pragma unroll
            for (int mt = 0; mt < 2; mt++)
                #pragma unroll
                for (int nt = 0; nt < 4; nt++)
                    acc[mt][nt] = __builtin_amdgcn_mfma_f32_16x16x32_bf16(af[mt], bf[nt], acc[mt][nt], 0, 0, 0);
        }
        __syncthreads();
        cur ^= 1;
    }
    #pragma unroll
    for (int nt = 0; nt < 4; nt++) {
        const int cn = n0 + wn * 64 + nt * 16 + col;
        const float bj = bias[cn];
        #pragma unroll
        for (int mt = 0; mt < 2; mt++) {
            const int rm = m0 + wm * 32 + mt * 16 + quad * 4;
            #pragma unroll
            for (int reg = 0; reg < 4; reg++) {
                float cv = acc[mt][nt][reg] + bj;
                if (RELU) cv = fmaxf(cv, 0.f);
                storeOut(&C[(size_t)(rm + reg) * N + cn], cv);
            }
        }
    }
}

// ---------------------------------------------------------------------------
// MFMA flash attention v9 (causal, reverse-paired tiles, COALESCED staging).
// R6-verified config (~56 us; R10: structure is round-throughput-bound).
// ---------------------------------------------------------------------------
__global__ __launch_bounds__(256, 2) void attn_mfma(const unsigned short* __restrict__ Qb,
                                                    const unsigned short* __restrict__ Kb,
                                                    const unsigned short* __restrict__ Vt,
                                                    __hip_bfloat16* __restrict__ O,
                                                    int L)
{
    __shared__ unsigned short Ks[2][4096];       // [buf][key:64][e-chunk swz] 16 KB
    __shared__ unsigned short Vs[2][4096];       // [buf][e:64][key-chunk swz] 16 KB
    __shared__ unsigned short PsA[4][16][72];    // per wave [qrow:16][key:64+pad] 9 KB
    __shared__ unsigned short PsB[4][16][72];

    const int i    = blockIdx.x;                 // 0..15
    const int bh   = blockIdx.y;
    const int b    = bh >> 3, h = bh & 7;        // H = 8
    const int t    = threadIdx.x;
    const int w    = t >> 6, lane = t & 63;
    const int quad = lane >> 4, col = lane & 15;

    const int qtA = i, qtB = 31 - i;             // light / heavy tile
    const int qrowA = qtA * 64 + w * 16 + col;
    const int qrowB = qtB * 64 + w * 16 + col;
    const int S = 32 - i;                        // rounds (tile B needs all)

    const int srow = lane >> 3;                  // row offset within instr (0..7)
    const int scp  = lane & 7;                   // destination chunk

    sh8 qfA[2], qfB[2];
    {
        const size_t qa = ((size_t)(b * L + qrowA) * 8 + h) * 64;
        qfA[0] = *(const sh8*)(Qb + qa + quad * 8);
        qfA[1] = *(const sh8*)(Qb + qa + 32 + quad * 8);
        const size_t qb2 = ((size_t)(b * L + qrowB) * 8 + h) * 64;
        qfB[0] = *(const sh8*)(Qb + qb2 + quad * 8);
        qfB[1] = *(const sh8*)(Qb + qb2 + 32 + quad * 8);
    }

    f32x4 OA[4], OB[4];
    #pragma unroll
    for (int nt = 0; nt < 4; nt++) { OA[nt] = (f32x4){0.f,0.f,0.f,0.f}; OB[nt] = (f32x4){0.f,0.f,0.f,0.f}; }
    float lA = 0.f, lB = 0.f;

    {
        #pragma unroll
        for (int seg = 0; seg < 2; seg++) {
            const int r0  = (seg * 4 + w) * 8;   // wave-uniform row base
            const int row = r0 + srow;
            const int ck  = scp ^ (row & 7);     // source chunk (involution)
            gl_lds16(Kb + ((size_t)(b * L + row) * 8 + h) * 64 + ck * 8, &Ks[0][r0 * 64]);
            gl_lds16(Vt + (size_t)(bh * 64 + row) * L + ck * 8, &Vs[0][r0 * 64]);
        }
        __syncthreads();
    }

    int cur = 0;
    for (int r = 0; r < S; r++) {
        if (r + 1 < S) {
            const int k1 = (r + 1) * 64;
            #pragma unroll
            for (int seg = 0; seg < 2; seg++) {
                const int r0  = (seg * 4 + w) * 8;
                const int row = r0 + srow;
                const int ck  = scp ^ (row & 7);
                gl_lds16(Kb + ((size_t)(b * L + k1 + row) * 8 + h) * 64 + ck * 8, &Ks[cur ^ 1][r0 * 64]);
                gl_lds16(Vt + (size_t)(bh * 64 + row) * L + k1 + ck * 8, &Vs[cur ^ 1][r0 * 64]);
            }
        }

        const int k0 = r * 64;
        const bool actA  = (r <= i);
        const bool maskA = (r == i);
        const bool maskB = (r == S - 1);

        f32x4 stA[4], stB[4];
        const f32x4 zz = {0.f, 0.f, 0.f, 0.f};
        #pragma unroll
        for (int ntk = 0; ntk < 4; ntk++) {
            const int key = ntk * 16 + col;
            const int sw  = key & 7;
            sh8 kf0 = *(const sh8*)&Ks[cur][key * 64 + ((quad ^ sw) << 3)];
            sh8 kf1 = *(const sh8*)&Ks[cur][key * 64 + (((quad + 4) ^ sw) << 3)];
            f32x4 aB = __builtin_amdgcn_mfma_f32_16x16x32_bf16(kf0, qfB[0], zz, 0, 0, 0);
            stB[ntk] = __builtin_amdgcn_mfma_f32_16x16x32_bf16(kf1, qfB[1], aB, 0, 0, 0);
            if (actA) {
                f32x4 aA = __builtin_amdgcn_mfma_f32_16x16x32_bf16(kf0, qfA[0], zz, 0, 0, 0);
                stA[ntk] = __builtin_amdgcn_mfma_f32_16x16x32_bf16(kf1, qfA[1], aA, 0, 0, 0);
            }
        }

        {
            if (maskB) {
                #pragma unroll
                for (int ntk = 0; ntk < 4; ntk++)
                    #pragma unroll
                    for (int reg = 0; reg < 4; reg++)
                        if (k0 + ntk * 16 + quad * 4 + reg > qrowB) stB[ntk][reg] = -1e30f;
            }
            #pragma unroll
            for (int ntk = 0; ntk < 4; ntk++) {
                #pragma unroll
                for (int reg = 0; reg < 4; reg++)
                    stB[ntk][reg] = exp2f(stB[ntk][reg]);
                lB += (stB[ntk][0] + stB[ntk][1]) + (stB[ntk][2] + stB[ntk][3]);
                *(uint2*)&PsB[w][col][ntk * 16 + quad * 4] =
                    make_uint2(pk_bf16(stB[ntk][0], stB[ntk][1]), pk_bf16(stB[ntk][2], stB[ntk][3]));
            }
        }
        if (actA) {
            if (maskA) {
                #pragma unroll
                for (int ntk = 0; ntk < 4; ntk++)
                    #pragma unroll
                    for (int reg = 0; reg < 4; reg++)
                        if (k0 + ntk * 16 + quad * 4 + reg > qrowA) stA[ntk][reg] = -1e30f;
            }
            #pragma unroll
            for (int ntk = 0; ntk < 4; ntk++) {
                #pragma unroll
                for (int reg = 0; reg < 4; reg++)
                    stA[ntk][reg] = exp2f(stA[ntk][reg]);
                lA += (stA[ntk][0] + stA[ntk][1]) + (stA[ntk][2] + stA[ntk][3]);
                *(uint2*)&PsA[w][col][ntk * 16 + quad * 4] =
                    make_uint2(pk_bf16(stA[ntk][0], stA[ntk][1]), pk_bf16(stA[ntk][2], stA[ntk][3]));
            }
        }

        #pragma unroll
        for (int kchunk = 0; kchunk < 2; kchunk++) {
            sh8 pfB = *(const sh8*)&PsB[w][col][kchunk * 32 + quad * 8];
            sh8 pfA;
            if (actA) pfA = *(const sh8*)&PsA[w][col][kchunk * 32 + quad * 8];
            #pragma unroll
            for (int nt = 0; nt < 4; nt++) {
                const int e  = nt * 16 + col;
                sh8 vf = *(const sh8*)&Vs[cur][e * 64 + (((kchunk * 4 + quad) ^ (e & 7)) << 3)];
                OB[nt] = __builtin_amdgcn_mfma_f32_16x16x32_bf16(pfB, vf, OB[nt], 0, 0, 0);
                if (actA) OA[nt] = __builtin_amdgcn_mfma_f32_16x16x32_bf16(pfA, vf, OA[nt], 0, 0, 0);
            }
        }
        __syncthreads();
        cur ^= 1;
    }

    lA += __shfl_xor(lA, 16); lA += __shfl_xor(lA, 32);
    lB += __shfl_xor(lB, 16); lB += __shfl_xor(lB, 32);
    {
        const float li = 1.f / lA;
        float lr[4];
        #pragma unroll
        for (int reg = 0; reg < 4; reg++) lr[reg] = __shfl(li, quad * 4 + reg);
        #pragma unroll
        for (int reg = 0; reg < 4; reg++) {
            const int qr = qtA * 64 + w * 16 + quad * 4 + reg;
            #pragma unroll
            for (int nt = 0; nt < 4; nt++)
                O[((size_t)(b * L + qr) * 8 + h) * 64 + nt * 16 + col] =
                    __float2bfloat16(OA[nt][reg] * lr[reg]);
        }
    }
    {
        const float li = 1.f / lB;
        float lr[4];
        #pragma unroll
        for (int reg = 0; reg < 4; reg++) lr[reg] = __shfl(li, quad * 4 + reg);
        #pragma unroll
        for (int reg = 0; reg < 4; reg++) {
            const int qr = qtB * 64 + w * 16 + quad * 4 + reg;
            #pragma unroll
            for (int nt = 0; nt < 4; nt++)
                O[((size_t)(b * L + qr) * 8 + h) * 64 + nt * 16 + col] =
                    __float2bfloat16(OB[nt][reg] * lr[reg]);
        }
    }
}

// ---------------------------------------------------------------------------
// LayerNorm over last dim (512), bf16 in / bf16 out (R12 diet).
// x = f1 [+ f2] [+ rb(fp32)]. In-place safe (reads precede writes/thread).
// ---------------------------------------------------------------------------
__global__ __launch_bounds__(256) void layernorm_k(const unsigned short* __restrict__ f1,
                                                   const unsigned short* __restrict__ f2,
                                                   const float* __restrict__ rb,
                                                   const float* __restrict__ g,
                                                   const float* __restrict__ bb,
                                                   unsigned short* __restrict__ out16)
{
    const int row = blockIdx.x;
    const int t   = threadIdx.x;
    const size_t base = (size_t)row * 512;
    const int i0 = t * 2;

    const unsigned u1 = *(const unsigned*)(f1 + base + i0);
    float a0 = bf2f((unsigned short)(u1 & 0xffff));
    float a1 = bf2f((unsigned short)(u1 >> 16));
    if (f2) {
        const unsigned u2 = *(const unsigned*)(f2 + base + i0);
        a0 += bf2f((unsigned short)(u2 & 0xffff));
        a1 += bf2f((unsigned short)(u2 >> 16));
    }
    if (rb) { a0 += rb[base + i0]; a1 += rb[base + i0 + 1]; }

    float s = a0 + a1, ss = a0 * a0 + a1 * a1;
    #pragma unroll
    for (int off = 32; off > 0; off >>= 1) {
        s  += __shfl_xor(s, off);
        ss += __shfl_xor(ss, off);
    }
    __shared__ float red[16];
    const int lane = t & 63, wid = t >> 6;
    if (lane == 0) { red[wid] = s; red[8 + wid] = ss; }
    __syncthreads();
    if (t == 0) {
        const float S  = red[0] + red[1] + red[2] + red[3];
        const float SS = red[8] + red[9] + red[10] + red[11];
        const float mu = S * (1.f / 512.f);
        const float var = SS * (1.f / 512.f) - mu * mu;
        red[0] = mu;
        red[1] = rsqrtf(fmaxf(var, 0.f) + 1e-5f);
    }
    __syncthreads();
    const float mu = red[0], rstd = red[1];
    const float y0 = (a0 - mu) * rstd * g[i0]     + bb[i0];
    const float y1 = (a1 - mu) * rstd * g[i0 + 1] + bb[i0 + 1];
    *(unsigned*)(out16 + base + i0) = pk_bf16(y0, y1);
}

// ---------------------------------------------------------------------------
extern "C" void kernel_launch(void* const* d_in, const int* in_sizes, int n_in,
                              void* d_out, int out_size, void* d_ws, size_t ws_size,
                              hipStream_t stream)
{
    const float* q   = (const float*)d_in[0];
    const float* k   = (const float*)d_in[1];
    const float* v   = (const float*)d_in[2];
    const float* Wq  = (const float*)d_in[3];
    const float* bq  = (const float*)d_in[4];
    const float* Wk  = (const float*)d_in[5];
    const float* bk  = (const float*)d_in[6];
    const float* Wv  = (const float*)d_in[7];
    const float* bv  = (const float*)d_in[8];
    const float* Wo  = (const float*)d_in[9];
    const float* bo  = (const float*)d_in[10];
    const float* Wc1 = (const float*)d_in[11];
    const float* bc1 = (const float*)d_in[12];
    const float* Wc2 = (const float*)d_in[13];
    const float* bc2 = (const float*)d_in[14];
    const float* g1  = (const float*)d_in[15];
    const float* b1  = (const float*)d_in[16];
    const float* g2  = (const float*)d_in[17];
    const float* b2  = (const float*)d_in[18];
    const float* Wl  = (const float*)d_in[19];
    const float* bl  = (const float*)d_in[20];
    float* out = (float*)d_out;

    const int B = 4, L = 2048, H = 8;
    const int M = B * L;                        // 8192

    // Workspace map (bytes):
    //   A2b (8 MB) at 40370176 (Wo out, dead after LN1).
    //   Y2b (8 MB) at 48758784 (FFN2 out, dead after LN2).
    //   X1b (16 MB) at 73924608, live LN1 -> FFN1 -> LN2 (in-place).
    char* base = (char*)d_ws;
    unsigned short* Wall = (unsigned short*)(base + 0);          // 6.8 MB, live all
    unsigned short* Wob  = (unsigned short*)(base + 1572864);
    unsigned short* Wlb  = (unsigned short*)(base + 2097152);
    unsigned short* Wc1b = (unsigned short*)(base + 2621440);
    unsigned short* Wc2b = (unsigned short*)(base + 4718592);
    unsigned short* Qb   = (unsigned short*)(base + 6815744);    // -> dead after attn
    unsigned short* Kb   = (unsigned short*)(base + 15204352);   // -> dead after attn
    unsigned short* Vt   = (unsigned short*)(base + 23592960);   // -> dead after attn
    unsigned short* A1   = (unsigned short*)(base + 31981568);   // -> dead after Wo
    unsigned short* A2b  = (unsigned short*)(base + 40370176);   // att@Wo bf16 -> dead after LN1
    unsigned short* Y2b  = (unsigned short*)(base + 48758784);   // FFN2 out bf16 -> dead after LN2
    unsigned short* X1b  = (unsigned short*)(base + 73924608);   // x bf16, live to LN2 (in-place)
    unsigned short* X2b  = (unsigned short*)(base + 73924608);   // = X1b (in-place LN2)
    unsigned short* H1   = (unsigned short*)(base + 6815744);    // 33.5 MB over Qb..A1
    const dim3 blk(256);

    // 1: weights fp32 -> bf16
    WArg wa;
    wa.w[0] = Wq; wa.w[1] = Wk; wa.w[2] = Wv; wa.w[3] = Wo; wa.w[4] = Wl;
    wa.w[5] = Wc1; wa.w[6] = Wc2; wa.wd = Wall;
    conv_w<<<dim3(3328), blk, 0, stream>>>(wa);

    // 2: batched QKV projections (fp32 A direct, BK=32 2-phase)
    QkvArg qa;
    qa.A0 = q;  qa.A1 = k;  qa.A2 = v;
    qa.b0 = bq; qa.b1 = bk; qa.b2 = bv;
    qa.C0 = Qb; qa.C1 = Kb; qa.Vt = Vt;
    gemm_qkv<<<dim3(4, 64, 3), blk, 0, stream>>>(qa, Wall, M, 512, 512);

    // 3: flash attention v9 (R6-verified) -> bf16 A1
    attn_mfma<<<dim3(16, B * H), blk, 0, stream>>>(Qb, Kb, Vt, (__hip_bfloat16*)A1, L);

    // 4: att @ Wo^T + bo -> bf16 A2b
    gemm_mfma64<__hip_bfloat16, false><<<dim3(4, 128), blk, 0, stream>>>(A1, Wob, bo, (__hip_bfloat16*)A2b, M, 512, 512);

    // 5: x = LN(A2b + v) -> bf16 X1b
    layernorm_k<<<dim3(M), blk, 0, stream>>>(A2b, nullptr, v, g1, b1, X1b);

    // 6: h1 = relu(x @ Wc1^T + bc1) -> bf16 [M,2048]
    gemm_mfma<__hip_bfloat16, true><<<dim3(16, 64), blk, 0, stream>>>(X1b, Wc1b, bc1, (__hip_bfloat16*)H1, M, 2048, 512);

    // 7: y2 = h1 @ Wc2^T + bc2 -> bf16 Y2b
    gemm_mfma64<__hip_bfloat16, false><<<dim3(4, 128), blk, 0, stream>>>(H1, Wc2b, bc2, (__hip_bfloat16*)Y2b, M, 512, 2048);

    // 8: x2 = LN(X1b + Y2b) -> bf16, in place on X1b
    layernorm_k<<<dim3(M), blk, 0, stream>>>(X1b, Y2b, nullptr, g2, b2, X2b);

    // 9: out = x2 @ Wl^T + bl -> fp32 d_out
    gemm_mfma64<float, false><<<dim3(4, 128), blk, 0, stream>>>(X2b, Wlb, bl, out, M, 512, 512);
}